// Round 16
// baseline (550.005 us; speedup 1.0000x reference)
//
#include <hip/hip_runtime.h>
#include <cmath>
#include <cstdint>

constexpr int T_STEPS = 512;
constexpr int BATCH   = 1024;
constexpr int DIM     = 128;
constexpr int LATENT  = 256;
constexpr int OUT_DIM = 64;
constexpr int ROWS    = 16;

typedef __attribute__((ext_vector_type(4))) float f32x4;
typedef __attribute__((ext_vector_type(4))) int   i32x4;

__device__ __forceinline__ float fast_tanh(float v) {
    float e = __builtin_amdgcn_exp2f(v * 2.885390081777927f);   // e^{2v}
    return __builtin_fmaf(-2.0f, __builtin_amdgcn_rcpf(e + 1.0f), 1.0f);
}
__device__ __forceinline__ float fast_sigmoid(float v) {
    float e = __builtin_amdgcn_exp2f(v * -1.4426950408889634f); // e^{-v}
    return __builtin_amdgcn_rcpf(e + 1.0f);
}
__device__ __forceinline__ int q8(float v, float inv) {
    return (int)__builtin_rintf(v * inv);
}
// x quant: fixed scale 32, clamp to +-127/32 (clip prob ~6e-5 per element)
__device__ __forceinline__ int q8x(float v) {
    return (int)__builtin_rintf(fminf(fmaxf(v, -3.96875f), 3.96875f) * 32.f);
}
__device__ __forceinline__ uint32_t pack4(int a, int b, int c, int d) {
    return (uint32_t)(a & 255) | ((uint32_t)(b & 255) << 8) |
           ((uint32_t)(c & 255) << 16) | ((uint32_t)(d & 255) << 24);
}
__device__ __forceinline__ int swz(int sl, int b) {
    return (sl ^ (b & 3) ^ ((b >> 2) & 3)) & 3;
}
// drain only LDS at the step barrier; global x prefetch floats across
__device__ __forceinline__ void barrier_lds_only() {
    asm volatile("s_waitcnt lgkmcnt(0)" ::: "memory");
    __builtin_amdgcn_s_barrier();
    asm volatile("" ::: "memory");
}

// generic per-column i8 A-frag loader: k = S*64 + kgrp*16 + j, col WC
#define WQJ(J) q8(_p[(size_t)(J) * LATENT], _inv)
#define LOADQ(NAME, MAT, WC, S, INV)                                        \
    i32x4 NAME; {                                                           \
        const float* _p = (MAT) + (size_t)((S) * 64 + kgrp * 16) * LATENT + (WC); \
        const float _inv = (INV);                                           \
        NAME[0] = (int)pack4(WQJ(0),  WQJ(1),  WQJ(2),  WQJ(3));            \
        NAME[1] = (int)pack4(WQJ(4),  WQJ(5),  WQJ(6),  WQJ(7));            \
        NAME[2] = (int)pack4(WQJ(8),  WQJ(9),  WQJ(10), WQJ(11));           \
        NAME[3] = (int)pack4(WQJ(12), WQJ(13), WQJ(14), WQJ(15));           \
    }

// grid = 64 blocks x 16 batch rows; block = 512 threads = 8 waves (2/SIMD).
// r10 fused structure, but the x-path is i8 too:
//   h: K=256 i8 -> 4 b128 B-frags; x: K=128 i8 -> 2 b128 B-frags
// -> 48 ds_read_b128/CU-step (r10: 64 — the dominant pipe), 12 MFMA/wave.
// Wh,Wi per-column i8 (scale colmax/127); h scale 127; x scale 32 (clamped).
__global__ __launch_bounds__(512)
void rnn_i8hx(const float* __restrict__ x,    // [512][1024][128]
              const float* __restrict__ h0,   // [1024][256]
              const float* __restrict__ Wi,   // [128][256]
              const float* __restrict__ bi,   // [256]
              const float* __restrict__ Wh,   // [256][256]
              const float* __restrict__ Wd,   // [256][64]
              const float* __restrict__ bd,   // [64]
              float* __restrict__ out)        // [1024][64]
{
    __shared__ __align__(16) uint8_t hls[2][4096];   // h i8, [4ksub][16][64B]
    __shared__ __align__(16) uint8_t xls[2][2048];   // x i8, [2ksub][16][64B]

    const int tid  = threadIdx.x;
    const int lane = tid & 63;
    const int wv   = tid >> 6;
    const int b0   = blockIdx.x * ROWS;
    const int b15  = lane & 15;
    const int kgrp = lane >> 4;
    const int tg0  = wv * 2, tg1 = wv * 2 + 1;
    const int wcol0 = tg0 * 16 + b15;
    const int wcol1 = wcol0 + 16;

    // ---- per-column max |Wh| (256 rows) and |Wi| (128 rows) ----
    float cmh0 = 0.f, cmh1 = 0.f, cmx0 = 0.f, cmx1 = 0.f;
    {
        const float* p0 = Wh + (size_t)(kgrp * 16) * LATENT + wcol0;
        #pragma unroll 4
        for (int i = 0; i < 64; ++i) {
            const size_t off = (size_t)((i >> 4) * 64 + (i & 15)) * LATENT;
            cmh0 = fmaxf(cmh0, fabsf(p0[off]));
            cmh1 = fmaxf(cmh1, fabsf(p0[off + 16]));
        }
        const float* q0 = Wi + (size_t)(kgrp * 16) * LATENT + wcol0;
        #pragma unroll 4
        for (int i = 0; i < 32; ++i) {
            const size_t off = (size_t)((i >> 4) * 64 + (i & 15)) * LATENT;
            cmx0 = fmaxf(cmx0, fabsf(q0[off]));
            cmx1 = fmaxf(cmx1, fabsf(q0[off + 16]));
        }
        cmh0 = fmaxf(cmh0, __shfl_xor(cmh0, 16));
        cmh0 = fmaxf(cmh0, __shfl_xor(cmh0, 32));
        cmh1 = fmaxf(cmh1, __shfl_xor(cmh1, 16));
        cmh1 = fmaxf(cmh1, __shfl_xor(cmh1, 32));
        cmx0 = fmaxf(cmx0, __shfl_xor(cmx0, 16));
        cmx0 = fmaxf(cmx0, __shfl_xor(cmx0, 32));
        cmx1 = fmaxf(cmx1, __shfl_xor(cmx1, 16));
        cmx1 = fmaxf(cmx1, __shfl_xor(cmx1, 32));
    }
    const float ih0 = cmh0 > 0.f ? 127.f / cmh0 : 0.f;
    const float ih1 = cmh1 > 0.f ? 127.f / cmh1 : 0.f;
    const float ix0 = cmx0 > 0.f ? 127.f / cmx0 : 0.f;
    const float ix1 = cmx1 > 0.f ? 127.f / cmx1 : 0.f;

    // ---- persistent A-frags: Wh i8 (4 ksub) + Wi i8 (2 ksub), 2 tiles ----
    LOADQ(AH0_0, Wh, wcol0, 0, ih0) LOADQ(AH0_1, Wh, wcol0, 1, ih0)
    LOADQ(AH0_2, Wh, wcol0, 2, ih0) LOADQ(AH0_3, Wh, wcol0, 3, ih0)
    LOADQ(AH1_0, Wh, wcol1, 0, ih1) LOADQ(AH1_1, Wh, wcol1, 1, ih1)
    LOADQ(AH1_2, Wh, wcol1, 2, ih1) LOADQ(AH1_3, Wh, wcol1, 3, ih1)
    LOADQ(AX0_0, Wi, wcol0, 0, ix0) LOADQ(AX0_1, Wi, wcol0, 1, ix0)
    LOADQ(AX1_0, Wi, wcol1, 0, ix1) LOADQ(AX1_1, Wi, wcol1, 1, ix1)

    // dequant scales + bias per (tile, reg r): col = tg*16 + kgrp*4 + r
    const float dh0_0 = __shfl(cmh0, kgrp * 4 + 0) * (1.f / 16129.f);
    const float dh0_1 = __shfl(cmh0, kgrp * 4 + 1) * (1.f / 16129.f);
    const float dh0_2 = __shfl(cmh0, kgrp * 4 + 2) * (1.f / 16129.f);
    const float dh0_3 = __shfl(cmh0, kgrp * 4 + 3) * (1.f / 16129.f);
    const float dh1_0 = __shfl(cmh1, kgrp * 4 + 0) * (1.f / 16129.f);
    const float dh1_1 = __shfl(cmh1, kgrp * 4 + 1) * (1.f / 16129.f);
    const float dh1_2 = __shfl(cmh1, kgrp * 4 + 2) * (1.f / 16129.f);
    const float dh1_3 = __shfl(cmh1, kgrp * 4 + 3) * (1.f / 16129.f);
    const float dx0_0 = __shfl(cmx0, kgrp * 4 + 0) * (1.f / 4064.f);
    const float dx0_1 = __shfl(cmx0, kgrp * 4 + 1) * (1.f / 4064.f);
    const float dx0_2 = __shfl(cmx0, kgrp * 4 + 2) * (1.f / 4064.f);
    const float dx0_3 = __shfl(cmx0, kgrp * 4 + 3) * (1.f / 4064.f);
    const float dx1_0 = __shfl(cmx1, kgrp * 4 + 0) * (1.f / 4064.f);
    const float dx1_1 = __shfl(cmx1, kgrp * 4 + 1) * (1.f / 4064.f);
    const float dx1_2 = __shfl(cmx1, kgrp * 4 + 2) * (1.f / 4064.f);
    const float dx1_3 = __shfl(cmx1, kgrp * 4 + 3) * (1.f / 4064.f);
    const float cb0_0 = bi[tg0 * 16 + kgrp * 4 + 0];
    const float cb0_1 = bi[tg0 * 16 + kgrp * 4 + 1];
    const float cb0_2 = bi[tg0 * 16 + kgrp * 4 + 2];
    const float cb0_3 = bi[tg0 * 16 + kgrp * 4 + 3];
    const float cb1_0 = bi[tg1 * 16 + kgrp * 4 + 0];
    const float cb1_1 = bi[tg1 * 16 + kgrp * 4 + 1];
    const float cb1_2 = bi[tg1 * 16 + kgrp * 4 + 2];
    const float cb1_3 = bi[tg1 * 16 + kgrp * 4 + 3];

    // ---- stage h0 (i8, uint2) and x(t=0) (i8, b32) ----
    const int pr = tid & 15;
    const int pq = tid >> 4;                // 0..31
    const int stb = (pq >> 3) * 1024 + pr * 64 +
                    (swz((pq >> 1) & 3, pr) << 4) + (pq & 1) * 8;
    const int stbx = (pq >> 4) * 1024 + pr * 64 +
                     (swz((pq >> 2) & 3, pr) << 4) + (pq & 3) * 4;
    {
        const float* hp = h0 + (size_t)(b0 + pr) * LATENT + pq * 8;
        uint32_t u0 = pack4(q8(hp[0], 127.f), q8(hp[1], 127.f),
                            q8(hp[2], 127.f), q8(hp[3], 127.f));
        uint32_t u1 = pack4(q8(hp[4], 127.f), q8(hp[5], 127.f),
                            q8(hp[6], 127.f), q8(hp[7], 127.f));
        *reinterpret_cast<uint2*>(&hls[0][stb]) = make_uint2(u0, u1);
        const float* xq = x + (size_t)(b0 + pr) * DIM + pq * 4;
        float4 xv = *reinterpret_cast<const float4*>(xq);
        *reinterpret_cast<uint32_t*>(&xls[0][stbx]) =
            pack4(q8x(xv.x), q8x(xv.y), q8x(xv.z), q8x(xv.w));
    }
    __syncthreads();

    const int hrd = b15 * 64 + (swz(kgrp, b15) << 4);   // shared by h and x
    const int wb0 = (tg0 >> 2) * 1024 + b15 * 64 +
                    (swz(tg0 & 3, b15) << 4) + kgrp * 4;
    const int wb1 = (tg1 >> 2) * 1024 + b15 * 64 +
                    (swz(tg1 & 3, b15) << 4) + kgrp * 4;
    const float* xp = x + ((size_t)BATCH + b0 + pr) * DIM + pq * 4;  // t=1

    int cur = 0;
    for (int t = 0; t < T_STEPS; ++t) {
        const bool pf = (t + 1 < T_STEPS);
        float4 xv;
        if (pf) {
            xv = *reinterpret_cast<const float4*>(xp);
            xp += (size_t)BATCH * DIM;
        }
        const uint8_t* hb = &hls[cur][hrd];
        const uint8_t* xb = &xls[cur][hrd];
        i32x4 bh0 = *reinterpret_cast<const i32x4*>(hb);
        i32x4 bh1 = *reinterpret_cast<const i32x4*>(hb + 1024);
        i32x4 bh2 = *reinterpret_cast<const i32x4*>(hb + 2048);
        i32x4 bh3 = *reinterpret_cast<const i32x4*>(hb + 3072);
        i32x4 bx0 = *reinterpret_cast<const i32x4*>(xb);
        i32x4 bx1 = *reinterpret_cast<const i32x4*>(xb + 1024);

        i32x4 ch0 = {0, 0, 0, 0}, ch1 = {0, 0, 0, 0};
        i32x4 cx0 = {0, 0, 0, 0}, cx1 = {0, 0, 0, 0};
        ch0 = __builtin_amdgcn_mfma_i32_16x16x64_i8(AH0_0, bh0, ch0, 0, 0, 0);
        ch1 = __builtin_amdgcn_mfma_i32_16x16x64_i8(AH1_0, bh0, ch1, 0, 0, 0);
        cx0 = __builtin_amdgcn_mfma_i32_16x16x64_i8(AX0_0, bx0, cx0, 0, 0, 0);
        cx1 = __builtin_amdgcn_mfma_i32_16x16x64_i8(AX1_0, bx0, cx1, 0, 0, 0);
        ch0 = __builtin_amdgcn_mfma_i32_16x16x64_i8(AH0_1, bh1, ch0, 0, 0, 0);
        ch1 = __builtin_amdgcn_mfma_i32_16x16x64_i8(AH1_1, bh1, ch1, 0, 0, 0);
        cx0 = __builtin_amdgcn_mfma_i32_16x16x64_i8(AX0_1, bx1, cx0, 0, 0, 0);
        cx1 = __builtin_amdgcn_mfma_i32_16x16x64_i8(AX1_1, bx1, cx1, 0, 0, 0);
        ch0 = __builtin_amdgcn_mfma_i32_16x16x64_i8(AH0_2, bh2, ch0, 0, 0, 0);
        ch1 = __builtin_amdgcn_mfma_i32_16x16x64_i8(AH1_2, bh2, ch1, 0, 0, 0);
        ch0 = __builtin_amdgcn_mfma_i32_16x16x64_i8(AH0_3, bh3, ch0, 0, 0, 0);
        ch1 = __builtin_amdgcn_mfma_i32_16x16x64_i8(AH1_3, bh3, ch1, 0, 0, 0);

        const int nxt = cur ^ 1;
        {   // tile0: h' = tanh(ch*dh + cx*dx + bias) -> i8 -> one b32
            float v0 = fast_tanh(__builtin_fmaf((float)ch0[0], dh0_0,
                        __builtin_fmaf((float)cx0[0], dx0_0, cb0_0)));
            float v1 = fast_tanh(__builtin_fmaf((float)ch0[1], dh0_1,
                        __builtin_fmaf((float)cx0[1], dx0_1, cb0_1)));
            float v2 = fast_tanh(__builtin_fmaf((float)ch0[2], dh0_2,
                        __builtin_fmaf((float)cx0[2], dx0_2, cb0_2)));
            float v3 = fast_tanh(__builtin_fmaf((float)ch0[3], dh0_3,
                        __builtin_fmaf((float)cx0[3], dx0_3, cb0_3)));
            *reinterpret_cast<uint32_t*>(&hls[nxt][wb0]) =
                pack4(q8(v0, 127.f), q8(v1, 127.f), q8(v2, 127.f), q8(v3, 127.f));
        }
        {   // tile1
            float v0 = fast_tanh(__builtin_fmaf((float)ch1[0], dh1_0,
                        __builtin_fmaf((float)cx1[0], dx1_0, cb1_0)));
            float v1 = fast_tanh(__builtin_fmaf((float)ch1[1], dh1_1,
                        __builtin_fmaf((float)cx1[1], dx1_1, cb1_1)));
            float v2 = fast_tanh(__builtin_fmaf((float)ch1[2], dh1_2,
                        __builtin_fmaf((float)cx1[2], dx1_2, cb1_2)));
            float v3 = fast_tanh(__builtin_fmaf((float)ch1[3], dh1_3,
                        __builtin_fmaf((float)cx1[3], dx1_3, cb1_3)));
            *reinterpret_cast<uint32_t*>(&hls[nxt][wb1]) =
                pack4(q8(v0, 127.f), q8(v1, 127.f), q8(v2, 127.f), q8(v3, 127.f));
        }
        if (pf)
            *reinterpret_cast<uint32_t*>(&xls[nxt][stbx]) =
                pack4(q8x(xv.x), q8x(xv.y), q8x(xv.z), q8x(xv.w));

        barrier_lds_only();
        cur = nxt;
    }

    // ---- decode: out = sigmoid(h/127 @ Wd + bd), 2 rows per thread ----
    {
        const int o  = tid & 63;
        const int rb = tid >> 6;            // rows rb, rb+8
        float s0 = 0.f, s1 = 0.f;
        #pragma unroll 4
        for (int k = 0; k < LATENT; k += 4) {
            const int sl   = (k >> 4) & 3;
            const int base = (k >> 6) * 1024 + (k & 15);
            const uint32_t pA = *reinterpret_cast<const uint32_t*>(
                &hls[cur][base + rb * 64 + (swz(sl, rb) << 4)]);
            const uint32_t pB = *reinterpret_cast<const uint32_t*>(
                &hls[cur][base + (rb + 8) * 64 + (swz(sl, rb + 8) << 4)]);
            const float w0 = Wd[(size_t)(k + 0) * OUT_DIM + o];
            const float w1 = Wd[(size_t)(k + 1) * OUT_DIM + o];
            const float w2 = Wd[(size_t)(k + 2) * OUT_DIM + o];
            const float w3 = Wd[(size_t)(k + 3) * OUT_DIM + o];
            s0 += (float)(int8_t)(pA) * w0 + (float)(int8_t)(pA >> 8) * w1
                + (float)(int8_t)(pA >> 16) * w2 + (float)(int8_t)(pA >> 24) * w3;
            s1 += (float)(int8_t)(pB) * w0 + (float)(int8_t)(pB >> 8) * w1
                + (float)(int8_t)(pB >> 16) * w2 + (float)(int8_t)(pB >> 24) * w3;
        }
        out[(size_t)(b0 + rb) * OUT_DIM + o] =
            fast_sigmoid(bd[o] + s0 * (1.f / 127.f));
        out[(size_t)(b0 + rb + 8) * OUT_DIM + o] =
            fast_sigmoid(bd[o] + s1 * (1.f / 127.f));
    }
}

extern "C" void kernel_launch(void* const* d_in, const int* in_sizes, int n_in,
                              void* d_out, int out_size, void* d_ws, size_t ws_size,
                              hipStream_t stream) {
    const float* x  = (const float*)d_in[0];
    const float* h0 = (const float*)d_in[1];
    const float* Wi = (const float*)d_in[2];
    const float* bi = (const float*)d_in[3];
    const float* Wh = (const float*)d_in[4];
    const float* Wd = (const float*)d_in[5];
    const float* bd = (const float*)d_in[6];
    float* out = (float*)d_out;

    hipLaunchKernelGGL(rnn_i8hx, dim3(BATCH / ROWS), dim3(512), 0, stream,
                       x, h0, Wi, bi, Wh, Wd, bd, out);
}

// Round 17
// 401.912 us; speedup vs baseline: 1.3685x; 1.3685x over previous
//
#include <hip/hip_runtime.h>
#include <cmath>
#include <cstdint>

constexpr int T_STEPS = 512;
constexpr int BATCH   = 1024;
constexpr int DIM     = 128;
constexpr int LATENT  = 256;
constexpr int OUT_DIM = 64;
constexpr int ROWS    = 16;

typedef __attribute__((ext_vector_type(8))) short bf16x8;
typedef __attribute__((ext_vector_type(4))) float f32x4;
typedef __attribute__((ext_vector_type(4))) int   i32x4;

__device__ __forceinline__ uint32_t f2bf(float f) {
    uint32_t u = __builtin_bit_cast(uint32_t, f);
    return (u + 0x7FFFu + ((u >> 16) & 1u)) >> 16;
}
__device__ __forceinline__ uint32_t pk2(float a, float b) {
    return f2bf(a) | (f2bf(b) << 16);
}
__device__ __forceinline__ float fast_tanh(float v) {
    float e = __builtin_amdgcn_exp2f(v * 2.885390081777927f);   // e^{2v}
    return __builtin_fmaf(-2.0f, __builtin_amdgcn_rcpf(e + 1.0f), 1.0f);
}
__device__ __forceinline__ float fast_sigmoid(float v) {
    float e = __builtin_amdgcn_exp2f(v * -1.4426950408889634f); // e^{-v}
    return __builtin_amdgcn_rcpf(e + 1.0f);
}
__device__ __forceinline__ int q8(float v, float inv) {
    return (int)__builtin_rintf(v * inv);
}
__device__ __forceinline__ uint32_t pack4(int a, int b, int c, int d) {
    return (uint32_t)(a & 255) | ((uint32_t)(b & 255) << 8) |
           ((uint32_t)(c & 255) << 16) | ((uint32_t)(d & 255) << 24);
}
// 16B-slot swizzle: phys_slot = sl ^ (b&3) ^ ((b>>2)&3)
__device__ __forceinline__ int swz(int sl, int b) {
    return (sl ^ (b & 3) ^ ((b >> 2) & 3)) & 3;
}

// grid = 64 blocks x 16 batch rows; block = 512 threads = 8 waves (2/SIMD).
// SWAPPED MFMA: C^T = W^T (A, persistent regs) x [h|x]^T (B, from LDS).
//   h-part: i8  mfma_i32_16x16x64_i8, 4 ksub (K=64) -> 4 b128 reads/wave
//   x-part: bf16 mfma_f32_16x16x32,   4 ksub (K=32) -> 4 b128 reads/wave
// Per-step/CU: 64 b128 LDS reads (~770cy) + 128 MFMA (~640cy/SIMD issue) —
// pipe-balanced; r11-r16 attacks on single pipes were all neutral/negative.
// Wh quantized per-column i8 (scale colmax/127), h at fixed scale 127.
__global__ __launch_bounds__(512)
void rnn_i8h(const float* __restrict__ x,    // [512][1024][128]
             const float* __restrict__ h0,   // [1024][256]
             const float* __restrict__ Wi,   // [128][256]
             const float* __restrict__ bi,   // [256]
             const float* __restrict__ Wh,   // [256][256]
             const float* __restrict__ Wd,   // [256][64]
             const float* __restrict__ bd,   // [64]
             float* __restrict__ out)        // [1024][64]
{
    __shared__ __align__(16) uint8_t hls[2][4096];   // h^T i8,  [4][16][64B]
    __shared__ __align__(16) uint8_t xls[2][4096];   // x^T bf16,[4][16][64B]

    const int tid  = threadIdx.x;
    const int lane = tid & 63;
    const int wv   = tid >> 6;              // 0..7
    const int b0   = blockIdx.x * ROWS;
    const int b15  = lane & 15;             // batch row (B col / C col)
    const int kgrp = lane >> 4;             // 0..3
    const int tg0  = wv * 2, tg1 = wv * 2 + 1;   // global 16-col tiles
    const int wcol0 = tg0 * 16 + b15;            // A row (output col), tile0
    const int wcol1 = wcol0 + 16;

    // ---- per-column max of |Wh| (for i8 scale), lane's 64-k share + shfl ----
    float cmh0 = 0.f, cmh1 = 0.f;
    {
        const float* p0 = Wh + (size_t)(kgrp * 16) * LATENT + wcol0;
        #pragma unroll 4
        for (int i = 0; i < 64; ++i) {
            const size_t off = (size_t)((i >> 4) * 64 + (i & 15)) * LATENT;
            cmh0 = fmaxf(cmh0, fabsf(p0[off]));
            cmh1 = fmaxf(cmh1, fabsf(p0[off + 16]));
        }
        cmh0 = fmaxf(cmh0, __shfl_xor(cmh0, 16));
        cmh0 = fmaxf(cmh0, __shfl_xor(cmh0, 32));
        cmh1 = fmaxf(cmh1, __shfl_xor(cmh1, 16));
        cmh1 = fmaxf(cmh1, __shfl_xor(cmh1, 32));
    }
    const float ih0 = cmh0 > 0.f ? 127.f / cmh0 : 0.f;
    const float ih1 = cmh1 > 0.f ? 127.f / cmh1 : 0.f;

    // ---- persistent A-frags: Wh (i8) and Wi (bf16) ----
#define WHQ(J) q8(_p[(size_t)(J) * LATENT], _inv)
#define LOADWH(NAME, WC, S, INV)                                            \
    i32x4 NAME; {                                                           \
        const float* _p = Wh + (size_t)((S) * 64 + kgrp * 16) * LATENT + (WC); \
        const float _inv = (INV);                                           \
        NAME[0] = (int)pack4(WHQ(0),  WHQ(1),  WHQ(2),  WHQ(3));            \
        NAME[1] = (int)pack4(WHQ(4),  WHQ(5),  WHQ(6),  WHQ(7));            \
        NAME[2] = (int)pack4(WHQ(8),  WHQ(9),  WHQ(10), WHQ(11));           \
        NAME[3] = (int)pack4(WHQ(12), WHQ(13), WHQ(14), WHQ(15));           \
    }
    LOADWH(AH0_0, wcol0, 0, ih0) LOADWH(AH0_1, wcol0, 1, ih0)
    LOADWH(AH0_2, wcol0, 2, ih0) LOADWH(AH0_3, wcol0, 3, ih0)
    LOADWH(AH1_0, wcol1, 0, ih1) LOADWH(AH1_1, wcol1, 1, ih1)
    LOADWH(AH1_2, wcol1, 2, ih1) LOADWH(AH1_3, wcol1, 3, ih1)

#define LOADWX(NAME, WC, S)                                                 \
    bf16x8 NAME; {                                                          \
        const float* _p = Wi + (size_t)((S) * 32 + kgrp * 8) * LATENT + (WC); \
        NAME[0] = (short)f2bf(_p[0]);                                       \
        NAME[1] = (short)f2bf(_p[(size_t)1 * LATENT]);                      \
        NAME[2] = (short)f2bf(_p[(size_t)2 * LATENT]);                      \
        NAME[3] = (short)f2bf(_p[(size_t)3 * LATENT]);                      \
        NAME[4] = (short)f2bf(_p[(size_t)4 * LATENT]);                      \
        NAME[5] = (short)f2bf(_p[(size_t)5 * LATENT]);                      \
        NAME[6] = (short)f2bf(_p[(size_t)6 * LATENT]);                      \
        NAME[7] = (short)f2bf(_p[(size_t)7 * LATENT]);                      \
    }
    LOADWX(AX0_0, wcol0, 0) LOADWX(AX0_1, wcol0, 1)
    LOADWX(AX0_2, wcol0, 2) LOADWX(AX0_3, wcol0, 3)
    LOADWX(AX1_0, wcol1, 0) LOADWX(AX1_1, wcol1, 1)
    LOADWX(AX1_2, wcol1, 2) LOADWX(AX1_3, wcol1, 3)

    // dequant scales + bias per (tile, reg r): wcol = tg*16 + kgrp*4 + r
    const float dh0_0 = __shfl(cmh0, kgrp * 4 + 0) * (1.f / 16129.f);
    const float dh0_1 = __shfl(cmh0, kgrp * 4 + 1) * (1.f / 16129.f);
    const float dh0_2 = __shfl(cmh0, kgrp * 4 + 2) * (1.f / 16129.f);
    const float dh0_3 = __shfl(cmh0, kgrp * 4 + 3) * (1.f / 16129.f);
    const float dh1_0 = __shfl(cmh1, kgrp * 4 + 0) * (1.f / 16129.f);
    const float dh1_1 = __shfl(cmh1, kgrp * 4 + 1) * (1.f / 16129.f);
    const float dh1_2 = __shfl(cmh1, kgrp * 4 + 2) * (1.f / 16129.f);
    const float dh1_3 = __shfl(cmh1, kgrp * 4 + 3) * (1.f / 16129.f);
    const float cb0_0 = bi[tg0 * 16 + kgrp * 4 + 0];
    const float cb0_1 = bi[tg0 * 16 + kgrp * 4 + 1];
    const float cb0_2 = bi[tg0 * 16 + kgrp * 4 + 2];
    const float cb0_3 = bi[tg0 * 16 + kgrp * 4 + 3];
    const float cb1_0 = bi[tg1 * 16 + kgrp * 4 + 0];
    const float cb1_1 = bi[tg1 * 16 + kgrp * 4 + 1];
    const float cb1_2 = bi[tg1 * 16 + kgrp * 4 + 2];
    const float cb1_3 = bi[tg1 * 16 + kgrp * 4 + 3];

    // ---- stage h0 (i8) and x(t=0) (bf16) ----
    const int pr = tid & 15;
    const int pq = tid >> 4;                // 0..31
    const int stb = (pq >> 3) * 1024 + pr * 64 +
                    (swz((pq >> 1) & 3, pr) << 4) + (pq & 1) * 8;
    {
        const float* hp = h0 + (size_t)(b0 + pr) * LATENT + pq * 8;
        uint32_t u0 = pack4(q8(hp[0], 127.f), q8(hp[1], 127.f),
                            q8(hp[2], 127.f), q8(hp[3], 127.f));
        uint32_t u1 = pack4(q8(hp[4], 127.f), q8(hp[5], 127.f),
                            q8(hp[6], 127.f), q8(hp[7], 127.f));
        *reinterpret_cast<uint2*>(&hls[0][stb]) = make_uint2(u0, u1);
        const float* xq = x + (size_t)(b0 + pr) * DIM + pq * 4;
        float4 xv = *reinterpret_cast<const float4*>(xq);
        *reinterpret_cast<uint2*>(&xls[0][stb]) =
            make_uint2(pk2(xv.x, xv.y), pk2(xv.z, xv.w));
    }
    __syncthreads();

    const int hrd = b15 * 64 + (swz(kgrp, b15) << 4);       // B-frag base
    const int wb0 = (tg0 >> 2) * 1024 + b15 * 64 +
                    (swz(tg0 & 3, b15) << 4) + kgrp * 4;
    const int wb1 = (tg1 >> 2) * 1024 + b15 * 64 +
                    (swz(tg1 & 3, b15) << 4) + kgrp * 4;
    const float* xp = x + ((size_t)BATCH + b0 + pr) * DIM + pq * 4;  // t=1

    int cur = 0;
    for (int t = 0; t < T_STEPS; ++t) {
        const bool pf = (t + 1 < T_STEPS);
        float4 xv;
        if (pf) {
            xv = *reinterpret_cast<const float4*>(xp);
            xp += (size_t)BATCH * DIM;
        }

        const uint8_t* hb = &hls[cur][hrd];
        const uint8_t* xb = &xls[cur][hrd];
        i32x4  bh0 = *reinterpret_cast<const i32x4*>(hb);
        i32x4  bh1 = *reinterpret_cast<const i32x4*>(hb + 1024);
        i32x4  bh2 = *reinterpret_cast<const i32x4*>(hb + 2048);
        i32x4  bh3 = *reinterpret_cast<const i32x4*>(hb + 3072);
        bf16x8 bx0 = *reinterpret_cast<const bf16x8*>(xb);
        bf16x8 bx1 = *reinterpret_cast<const bf16x8*>(xb + 1024);
        bf16x8 bx2 = *reinterpret_cast<const bf16x8*>(xb + 2048);
        bf16x8 bx3 = *reinterpret_cast<const bf16x8*>(xb + 3072);

        i32x4 ch0 = {0, 0, 0, 0}, ch1 = {0, 0, 0, 0};
        f32x4 cx0 = {cb0_0, cb0_1, cb0_2, cb0_3};
        f32x4 cx1 = {cb1_0, cb1_1, cb1_2, cb1_3};

        ch0 = __builtin_amdgcn_mfma_i32_16x16x64_i8(AH0_0, bh0, ch0, 0, 0, 0);
        ch1 = __builtin_amdgcn_mfma_i32_16x16x64_i8(AH1_0, bh0, ch1, 0, 0, 0);
        cx0 = __builtin_amdgcn_mfma_f32_16x16x32_bf16(AX0_0, bx0, cx0, 0, 0, 0);
        cx1 = __builtin_amdgcn_mfma_f32_16x16x32_bf16(AX1_0, bx0, cx1, 0, 0, 0);
        ch0 = __builtin_amdgcn_mfma_i32_16x16x64_i8(AH0_1, bh1, ch0, 0, 0, 0);
        ch1 = __builtin_amdgcn_mfma_i32_16x16x64_i8(AH1_1, bh1, ch1, 0, 0, 0);
        cx0 = __builtin_amdgcn_mfma_f32_16x16x32_bf16(AX0_1, bx1, cx0, 0, 0, 0);
        cx1 = __builtin_amdgcn_mfma_f32_16x16x32_bf16(AX1_1, bx1, cx1, 0, 0, 0);
        ch0 = __builtin_amdgcn_mfma_i32_16x16x64_i8(AH0_2, bh2, ch0, 0, 0, 0);
        ch1 = __builtin_amdgcn_mfma_i32_16x16x64_i8(AH1_2, bh2, ch1, 0, 0, 0);
        cx0 = __builtin_amdgcn_mfma_f32_16x16x32_bf16(AX0_2, bx2, cx0, 0, 0, 0);
        cx1 = __builtin_amdgcn_mfma_f32_16x16x32_bf16(AX1_2, bx2, cx1, 0, 0, 0);
        ch0 = __builtin_amdgcn_mfma_i32_16x16x64_i8(AH0_3, bh3, ch0, 0, 0, 0);
        ch1 = __builtin_amdgcn_mfma_i32_16x16x64_i8(AH1_3, bh3, ch1, 0, 0, 0);
        cx0 = __builtin_amdgcn_mfma_f32_16x16x32_bf16(AX0_3, bx3, cx0, 0, 0, 0);
        cx1 = __builtin_amdgcn_mfma_f32_16x16x32_bf16(AX1_3, bx3, cx1, 0, 0, 0);

        const int nxt = cur ^ 1;
        {   // tile0: combine (bias in cx init) -> tanh -> i8 -> one b32 write
            float v0 = fast_tanh(__builtin_fmaf((float)ch0[0], dh0_0, cx0[0]));
            float v1 = fast_tanh(__builtin_fmaf((float)ch0[1], dh0_1, cx0[1]));
            float v2 = fast_tanh(__builtin_fmaf((float)ch0[2], dh0_2, cx0[2]));
            float v3 = fast_tanh(__builtin_fmaf((float)ch0[3], dh0_3, cx0[3]));
            *reinterpret_cast<uint32_t*>(&hls[nxt][wb0]) =
                pack4(q8(v0, 127.f), q8(v1, 127.f), q8(v2, 127.f), q8(v3, 127.f));
        }
        {   // tile1
            float v0 = fast_tanh(__builtin_fmaf((float)ch1[0], dh1_0, cx1[0]));
            float v1 = fast_tanh(__builtin_fmaf((float)ch1[1], dh1_1, cx1[1]));
            float v2 = fast_tanh(__builtin_fmaf((float)ch1[2], dh1_2, cx1[2]));
            float v3 = fast_tanh(__builtin_fmaf((float)ch1[3], dh1_3, cx1[3]));
            *reinterpret_cast<uint32_t*>(&hls[nxt][wb1]) =
                pack4(q8(v0, 127.f), q8(v1, 127.f), q8(v2, 127.f), q8(v3, 127.f));
        }
        if (pf)
            *reinterpret_cast<uint2*>(&xls[nxt][stb]) =
                make_uint2(pk2(xv.x, xv.y), pk2(xv.z, xv.w));

        __syncthreads();
        cur = nxt;
    }

    // ---- decode: out = sigmoid(h/127 @ Wd + bd), 2 rows per thread ----
    {
        const int o  = tid & 63;
        const int rb = tid >> 6;            // rows rb, rb+8
        float s0 = 0.f, s1 = 0.f;
        #pragma unroll 4
        for (int k = 0; k < LATENT; k += 4) {
            const int sl   = (k >> 4) & 3;
            const int base = (k >> 6) * 1024 + (k & 15);
            const uint32_t pA = *reinterpret_cast<const uint32_t*>(
                &hls[cur][base + rb * 64 + (swz(sl, rb) << 4)]);
            const uint32_t pB = *reinterpret_cast<const uint32_t*>(
                &hls[cur][base + (rb + 8) * 64 + (swz(sl, rb + 8) << 4)]);
            const float w0 = Wd[(size_t)(k + 0) * OUT_DIM + o];
            const float w1 = Wd[(size_t)(k + 1) * OUT_DIM + o];
            const float w2 = Wd[(size_t)(k + 2) * OUT_DIM + o];
            const float w3 = Wd[(size_t)(k + 3) * OUT_DIM + o];
            s0 += (float)(int8_t)(pA) * w0 + (float)(int8_t)(pA >> 8) * w1
                + (float)(int8_t)(pA >> 16) * w2 + (float)(int8_t)(pA >> 24) * w3;
            s1 += (float)(int8_t)(pB) * w0 + (float)(int8_t)(pB >> 8) * w1
                + (float)(int8_t)(pB >> 16) * w2 + (float)(int8_t)(pB >> 24) * w3;
        }
        out[(size_t)(b0 + rb) * OUT_DIM + o] =
            fast_sigmoid(bd[o] + s0 * (1.f / 127.f));
        out[(size_t)(b0 + rb + 8) * OUT_DIM + o] =
            fast_sigmoid(bd[o] + s1 * (1.f / 127.f));
    }
}

extern "C" void kernel_launch(void* const* d_in, const int* in_sizes, int n_in,
                              void* d_out, int out_size, void* d_ws, size_t ws_size,
                              hipStream_t stream) {
    const float* x  = (const float*)d_in[0];
    const float* h0 = (const float*)d_in[1];
    const float* Wi = (const float*)d_in[2];
    const float* bi = (const float*)d_in[3];
    const float* Wh = (const float*)d_in[4];
    const float* Wd = (const float*)d_in[5];
    const float* bd = (const float*)d_in[6];
    float* out = (float*)d_out;

    hipLaunchKernelGGL(rnn_i8h, dim3(BATCH / ROWS), dim3(512), 0, stream,
                       x, h0, Wi, bi, Wh, Wd, bd, out);
}